// Round 2
// baseline (88.613 us; speedup 1.0000x reference)
//
#include <hip/hip_runtime.h>
#include <math.h>

constexpr int C = 512;
constexpr int H = 50;
constexpr int W = 75;
constexpr int NROI = 512;
constexpr int PLANE = H * W;        // 3750
constexpr int PPAD  = 3840;         // padded plane; px 3750..3839 zeroed (OOB corners, weight 0)
constexpr int NG = C / 4;           // 128 channel groups of 4
constexpr int RSPLIT = 4;
constexpr int RPB = NROI / RSPLIT;  // 128 ROIs per block
constexpr int THREADS = 512;        // 8 waves/block
constexpr float INV_STRIDE = 1.0f / 16.0f;

typedef _Float16 h2 __attribute__((ext_vector_type(2)));
struct alignas(8) px4 { h2 a, b; }; // one pixel, 4 packed fp16 channels (8 B)

// ---------------------------------------------------------------------------
// Block = (4-ch group g, 128-ROI chunk): 512 blocks x 512 threads,
// 59.4 KB LDS -> 2 blocks/CU, exactly one scheduling round (256 CU x 2).
//
// R1 post-mortem: RSPLIT 16->4 (staging traffic /4) bought only 2.7us of a
// modeled 12 -> kernel is NOT staging-bound. All throughput models (LDS
// gather ~12us, stores ~9us, VALU ~4us) sit 2x under the ~42us measured ->
// latency/ILP-bound. Prime suspect: __launch_bounds__(...,8) caps VGPR at
// 64, so the "issue all 8 gathers first" batch (32+ VGPR of results) can't
// live in registers and the compiler serializes lgkmcnt waits.
// This round: __launch_bounds__(512, 4) -> 128-VGPR budget, 4 waves/SIMD.
// Half the waves, double the per-wave MLP: the 8-gather batch + cross-quad
// overlap (12 independent rounds/thread) should hide LDS latency.
// ---------------------------------------------------------------------------
__global__ __launch_bounds__(THREADS, 4) void roialign_fused(const float* __restrict__ bottom,
                                                             const float* __restrict__ rois,
                                                             float* __restrict__ out)
{
    __shared__ px4  plane[PPAD];         // 30720 B
    __shared__ uint4 xlds[RPB * 7];      // [rl][pw] = {offL, wL(h2 w0,w1), offR, wR}  14336 B
    __shared__ uint4 ylds[RPB * 7];      // [rl][ph] = {roffT, wT,          roffB, wB} 14336 B

    int g = blockIdx.x;
    int rbase = blockIdx.y * RPB;
    int t = threadIdx.x;

    // ---- fused staging: convert this block's 4 channels f32 -> px4 in LDS ----
    {
        const float* s0 = bottom + (4 * g + 0) * PLANE;
        const float* s1 = bottom + (4 * g + 1) * PLANE;
        const float* s2 = bottom + (4 * g + 2) * PLANE;
        const float* s3 = bottom + (4 * g + 3) * PLANE;
        for (int i = t; i < PPAD; i += THREADS) {
            px4 v;
            if (i < PLANE) {
                v.a = (h2){(_Float16)s0[i], (_Float16)s1[i]};
                v.b = (h2){(_Float16)s2[i], (_Float16)s3[i]};
            } else {
                v.a = (h2){(_Float16)0.0f, (_Float16)0.0f};
                v.b = v.a;
            }
            plane[i] = v;
        }
    }

    // ---- per-ROI interpolation descriptors (same math as all passing rounds) ----
    {
        uint2* xl2 = (uint2*)xlds;
        uint2* yl2 = (uint2*)ylds;
        for (int e = t; e < RPB * 28; e += THREADS) {
            int rl = e / 28;
            int tt = e - rl * 28;
            bool isx = tt < 14;
            int j = isx ? tt : tt - 14;
            const float* r = rois + (rbase + rl) * 5;
            float lo = (isx ? r[1] : r[2]) * INV_STRIDE;
            float hi = (isx ? r[3] : r[4]) * INV_STRIDE;
            float cc = 0.5f * (lo + hi), dd = 0.5f * (hi - lo);
            float b = -1.0f + (2.0f / 13.0f) * (float)j;
            float x  = fmaf(dd, b, cc);
            float xf = floorf(x);
            int ix = (int)xf;
            float f = x - xf;
            int lim = isx ? (W - 1) : (H - 1);
            bool v0 = (ix >= 0) && (ix <= lim);
            bool v1 = (ix + 1 >= 0) && (ix + 1 <= lim);
            int off = min(max(ix, 0), lim) * (isx ? 1 : W);
            float w0 = v0 ? (1.0f - f) : 0.0f;
            float w1 = v1 ? f : 0.0f;
            h2 wboth = (h2){(_Float16)w0, (_Float16)w1};
            uint2 d;
            d.x = (unsigned)off;
            d.y = __builtin_bit_cast(unsigned, wboth);
            (isx ? xl2 : yl2)[rl * 14 + j] = d;
        }
    }
    __syncthreads();

    // ---- gather + bilinear + maxpool ----
    auto do_quad = [&](int s) {
        int rl  = s / 49;               // magic-mul
        int s49 = s - rl * 49;
        int ph  = s49 / 7;
        int pw  = s49 - ph * 7;

        uint4 xd = xlds[rl * 7 + pw];   // {offL, wL, offR, wR}
        uint4 yd = ylds[rl * 7 + ph];   // {roffT, wT, roffB, wB}

        // issue ALL 8 gathers first (4 samples x 2 ds_read2_b64)
        const px4* pTL = plane + (int)yd.x + (int)xd.x;
        const px4* pTR = plane + (int)yd.x + (int)xd.z;
        const px4* pBL = plane + (int)yd.z + (int)xd.x;
        const px4* pBR = plane + (int)yd.z + (int)xd.z;
        px4 tl0 = pTL[0], tl1 = pTL[1], tl2 = pTL[W], tl3 = pTL[W + 1];
        px4 tr0 = pTR[0], tr1 = pTR[1], tr2 = pTR[W], tr3 = pTR[W + 1];
        px4 bl0 = pBL[0], bl1 = pBL[1], bl2 = pBL[W], bl3 = pBL[W + 1];
        px4 br0 = pBR[0], br1 = pBR[1], br2 = pBR[W], br3 = pBR[W + 1];

        h2 wxL = __builtin_bit_cast(h2, xd.y);
        h2 wxR = __builtin_bit_cast(h2, xd.w);
        h2 wyT = __builtin_bit_cast(h2, yd.y);
        h2 wyB = __builtin_bit_cast(h2, yd.w);

        auto lerp2 = [](px4 q0, px4 q1, px4 q2, px4 q3, h2 wx, h2 wy) -> px4 {
            h2 wx0 = __builtin_shufflevector(wx, wx, 0, 0);
            h2 wx1 = __builtin_shufflevector(wx, wx, 1, 1);
            h2 wy0 = __builtin_shufflevector(wy, wy, 0, 0);
            h2 wy1 = __builtin_shufflevector(wy, wy, 1, 1);
            px4 v;
            v.a = wy0 * (wx0 * q0.a + wx1 * q1.a) + wy1 * (wx0 * q2.a + wx1 * q3.a);
            v.b = wy0 * (wx0 * q0.b + wx1 * q1.b) + wy1 * (wx0 * q2.b + wx1 * q3.b);
            return v;
        };

        px4 vTL = lerp2(tl0, tl1, tl2, tl3, wxL, wyT);
        px4 vTR = lerp2(tr0, tr1, tr2, tr3, wxR, wyT);
        px4 vBL = lerp2(bl0, bl1, bl2, bl3, wxL, wyB);
        px4 vBR = lerp2(br0, br1, br2, br3, wxR, wyB);

        h2 ma = __builtin_elementwise_max(__builtin_elementwise_max(vTL.a, vTR.a),
                                          __builtin_elementwise_max(vBL.a, vBR.a));
        h2 mb = __builtin_elementwise_max(__builtin_elementwise_max(vTL.b, vTR.b),
                                          __builtin_elementwise_max(vBL.b, vBR.b));

        float* ob = out + (size_t)((rbase + rl) * C + 4 * g) * 49 + s49;
        ob[0]   = (float)ma.x;
        ob[49]  = (float)ma.y;
        ob[98]  = (float)mb.x;
        ob[147] = (float)mb.y;
    };

    // 6272 quads over 512 threads: 12 full rounds + tail for t<128
    #pragma unroll
    for (int k = 0; k < 12; ++k) do_quad(t + k * THREADS);
    if (t < 128) do_quad(t + 12 * THREADS);
}

extern "C" void kernel_launch(void* const* d_in, const int* in_sizes, int n_in,
                              void* d_out, int out_size, void* d_ws, size_t ws_size,
                              hipStream_t stream) {
    const float* bottom = (const float*)d_in[0];
    const float* rois   = (const float*)d_in[1];
    float* out = (float*)d_out;

    dim3 grid(NG, RSPLIT); // 128 x 4 = 512 blocks, exactly 2/CU
    roialign_fused<<<grid, THREADS, 0, stream>>>(bottom, rois, out);
}

// Round 3
// 87.595 us; speedup vs baseline: 1.0116x; 1.0116x over previous
//
#include <hip/hip_runtime.h>
#include <math.h>

constexpr int C = 512;
constexpr int H = 50;
constexpr int W = 75;
constexpr int NROI = 512;
constexpr int PLANE = H * W;        // 3750
constexpr int PPAD  = 3840;         // padded plane; px 3750..3839 zeroed (OOB corners, weight 0)
constexpr int NG = C / 4;           // 128 channel groups of 4
constexpr int RSPLIT = 4;
constexpr int RPB = NROI / RSPLIT;  // 128 ROIs per block
constexpr int THREADS = 512;        // 8 waves/block
constexpr float INV_STRIDE = 1.0f / 16.0f;

typedef _Float16 h2 __attribute__((ext_vector_type(2)));
struct alignas(8) px4 { h2 a, b; }; // one pixel, 4 packed fp16 channels (8 B)

// ---------------------------------------------------------------------------
// R3: decisive ILP experiment. R1 (staging/4: -2.7us) and R2 (128-VGPR
// budget: +1.7us) both landed in noise -> either the kernel serializes
// per-quad at the SOURCE level (compiler won't merge gather batches across
// do_quad calls), or the kernel is already at its ~20us structural model
// and dur_us is dominated by the harness's 256MiB ws-poison fill (~45us,
// the only dispatches visible in rocprof top-5).
// This round: explicit QUAD-PAIR pipelining — decode 2 quads, read 4
// descriptors, compute 8 pointers, issue all 16 ds_read2_b64 (64 VGPR of
// results, fits the 128-VGPR bounds(512,4) budget) before any math; plus
// float2 staging loads (channel stride 15000B is 8B-aligned, not 16B).
// Pre-committed fork: -8..-10us => ILP theory (A) right, keep pushing;
// +-2us => fixed-cost theory (B) confirmed by elimination -> roofline.
// ---------------------------------------------------------------------------
__global__ __launch_bounds__(THREADS, 4) void roialign_fused(const float* __restrict__ bottom,
                                                             const float* __restrict__ rois,
                                                             float* __restrict__ out)
{
    __shared__ px4  plane[PPAD];         // 30720 B
    __shared__ uint4 xlds[RPB * 7];      // [rl][pw] = {offL, wL(h2 w0,w1), offR, wR}  14336 B
    __shared__ uint4 ylds[RPB * 7];      // [rl][ph] = {roffT, wT,          roffB, wB} 14336 B

    int g = blockIdx.x;
    int rbase = blockIdx.y * RPB;
    int t = threadIdx.x;

    // ---- fused staging: f32 -> px4 in LDS, float2-vectorized (1875 pairs) ----
    {
        const float2* s0 = (const float2*)(bottom + (4 * g + 0) * PLANE);
        const float2* s1 = (const float2*)(bottom + (4 * g + 1) * PLANE);
        const float2* s2 = (const float2*)(bottom + (4 * g + 2) * PLANE);
        const float2* s3 = (const float2*)(bottom + (4 * g + 3) * PLANE);
        #pragma unroll
        for (int k = 0; k < 4; ++k) {
            int i = t + k * THREADS;           // pair index, 0..1874
            if (i < PLANE / 2) {
                float2 v0 = s0[i], v1 = s1[i], v2 = s2[i], v3 = s3[i];
                px4 p0, p1;
                p0.a = (h2){(_Float16)v0.x, (_Float16)v1.x};
                p0.b = (h2){(_Float16)v2.x, (_Float16)v3.x};
                p1.a = (h2){(_Float16)v0.y, (_Float16)v1.y};
                p1.b = (h2){(_Float16)v2.y, (_Float16)v3.y};
                plane[2 * i]     = p0;
                plane[2 * i + 1] = p1;
            }
        }
        if (t < PPAD - PLANE) {                // zero pad 3750..3839
            px4 z;
            z.a = (h2){(_Float16)0.0f, (_Float16)0.0f};
            z.b = z.a;
            plane[PLANE + t] = z;
        }
    }

    // ---- per-ROI interpolation descriptors (same math as all passing rounds) ----
    {
        uint2* xl2 = (uint2*)xlds;
        uint2* yl2 = (uint2*)ylds;
        for (int e = t; e < RPB * 28; e += THREADS) {
            int rl = e / 28;
            int tt = e - rl * 28;
            bool isx = tt < 14;
            int j = isx ? tt : tt - 14;
            const float* r = rois + (rbase + rl) * 5;
            float lo = (isx ? r[1] : r[2]) * INV_STRIDE;
            float hi = (isx ? r[3] : r[4]) * INV_STRIDE;
            float cc = 0.5f * (lo + hi), dd = 0.5f * (hi - lo);
            float b = -1.0f + (2.0f / 13.0f) * (float)j;
            float x  = fmaf(dd, b, cc);
            float xf = floorf(x);
            int ix = (int)xf;
            float f = x - xf;
            int lim = isx ? (W - 1) : (H - 1);
            bool v0 = (ix >= 0) && (ix <= lim);
            bool v1 = (ix + 1 >= 0) && (ix + 1 <= lim);
            int off = min(max(ix, 0), lim) * (isx ? 1 : W);
            float w0 = v0 ? (1.0f - f) : 0.0f;
            float w1 = v1 ? f : 0.0f;
            h2 wboth = (h2){(_Float16)w0, (_Float16)w1};
            uint2 d;
            d.x = (unsigned)off;
            d.y = __builtin_bit_cast(unsigned, wboth);
            (isx ? xl2 : yl2)[rl * 14 + j] = d;
        }
    }
    __syncthreads();

    auto lerp2 = [](px4 q0, px4 q1, px4 q2, px4 q3, h2 wx, h2 wy) -> px4 {
        h2 wx0 = __builtin_shufflevector(wx, wx, 0, 0);
        h2 wx1 = __builtin_shufflevector(wx, wx, 1, 1);
        h2 wy0 = __builtin_shufflevector(wy, wy, 0, 0);
        h2 wy1 = __builtin_shufflevector(wy, wy, 1, 1);
        px4 v;
        v.a = wy0 * (wx0 * q0.a + wx1 * q1.a) + wy1 * (wx0 * q2.a + wx1 * q3.a);
        v.b = wy0 * (wx0 * q0.b + wx1 * q1.b) + wy1 * (wx0 * q2.b + wx1 * q3.b);
        return v;
    };

    auto finish = [&](px4 vTL, px4 vTR, px4 vBL, px4 vBR, int rl, int s49) {
        h2 ma = __builtin_elementwise_max(__builtin_elementwise_max(vTL.a, vTR.a),
                                          __builtin_elementwise_max(vBL.a, vBR.a));
        h2 mb = __builtin_elementwise_max(__builtin_elementwise_max(vTL.b, vTR.b),
                                          __builtin_elementwise_max(vBL.b, vBR.b));
        float* ob = out + (size_t)((rbase + rl) * C + 4 * g) * 49 + s49;
        ob[0]   = (float)ma.x;
        ob[49]  = (float)ma.y;
        ob[98]  = (float)mb.x;
        ob[147] = (float)mb.y;
    };

    // ---- paired gather + bilinear + maxpool: 16 ds_read2_b64 in flight ----
    auto do_pair = [&](int sA, int sB) {
        int rlA = sA / 49, aA = sA - rlA * 49, phA = aA / 7, pwA = aA - phA * 7;
        int rlB = sB / 49, aB = sB - rlB * 49, phB = aB / 7, pwB = aB - phB * 7;

        uint4 xdA = xlds[rlA * 7 + pwA];
        uint4 ydA = ylds[rlA * 7 + phA];
        uint4 xdB = xlds[rlB * 7 + pwB];
        uint4 ydB = ylds[rlB * 7 + phB];

        const px4* A_TL = plane + (int)ydA.x + (int)xdA.x;
        const px4* A_TR = plane + (int)ydA.x + (int)xdA.z;
        const px4* A_BL = plane + (int)ydA.z + (int)xdA.x;
        const px4* A_BR = plane + (int)ydA.z + (int)xdA.z;
        const px4* B_TL = plane + (int)ydB.x + (int)xdB.x;
        const px4* B_TR = plane + (int)ydB.x + (int)xdB.z;
        const px4* B_BL = plane + (int)ydB.z + (int)xdB.x;
        const px4* B_BR = plane + (int)ydB.z + (int)xdB.z;

        // 32 px4 loads (16 ds_read2_b64), all issued before any math
        px4 atl0 = A_TL[0], atl1 = A_TL[1], atl2 = A_TL[W], atl3 = A_TL[W + 1];
        px4 atr0 = A_TR[0], atr1 = A_TR[1], atr2 = A_TR[W], atr3 = A_TR[W + 1];
        px4 abl0 = A_BL[0], abl1 = A_BL[1], abl2 = A_BL[W], abl3 = A_BL[W + 1];
        px4 abr0 = A_BR[0], abr1 = A_BR[1], abr2 = A_BR[W], abr3 = A_BR[W + 1];
        px4 btl0 = B_TL[0], btl1 = B_TL[1], btl2 = B_TL[W], btl3 = B_TL[W + 1];
        px4 btr0 = B_TR[0], btr1 = B_TR[1], btr2 = B_TR[W], btr3 = B_TR[W + 1];
        px4 bbl0 = B_BL[0], bbl1 = B_BL[1], bbl2 = B_BL[W], bbl3 = B_BL[W + 1];
        px4 bbr0 = B_BR[0], bbr1 = B_BR[1], bbr2 = B_BR[W], bbr3 = B_BR[W + 1];

        h2 wxLA = __builtin_bit_cast(h2, xdA.y), wxRA = __builtin_bit_cast(h2, xdA.w);
        h2 wyTA = __builtin_bit_cast(h2, ydA.y), wyBA = __builtin_bit_cast(h2, ydA.w);
        h2 wxLB = __builtin_bit_cast(h2, xdB.y), wxRB = __builtin_bit_cast(h2, xdB.w);
        h2 wyTB = __builtin_bit_cast(h2, ydB.y), wyBB = __builtin_bit_cast(h2, ydB.w);

        finish(lerp2(atl0, atl1, atl2, atl3, wxLA, wyTA),
               lerp2(atr0, atr1, atr2, atr3, wxRA, wyTA),
               lerp2(abl0, abl1, abl2, abl3, wxLA, wyBA),
               lerp2(abr0, abr1, abr2, abr3, wxRA, wyBA), rlA, aA);
        finish(lerp2(btl0, btl1, btl2, btl3, wxLB, wyTB),
               lerp2(btr0, btr1, btr2, btr3, wxRB, wyTB),
               lerp2(bbl0, bbl1, bbl2, bbl3, wxLB, wyBB),
               lerp2(bbr0, bbr1, bbr2, bbr3, wxRB, wyBB), rlB, aB);
    };

    auto do_single = [&](int s) {
        int rl = s / 49, s49 = s - rl * 49, ph = s49 / 7, pw = s49 - ph * 7;
        uint4 xd = xlds[rl * 7 + pw];
        uint4 yd = ylds[rl * 7 + ph];
        const px4* pTL = plane + (int)yd.x + (int)xd.x;
        const px4* pTR = plane + (int)yd.x + (int)xd.z;
        const px4* pBL = plane + (int)yd.z + (int)xd.x;
        const px4* pBR = plane + (int)yd.z + (int)xd.z;
        px4 tl0 = pTL[0], tl1 = pTL[1], tl2 = pTL[W], tl3 = pTL[W + 1];
        px4 tr0 = pTR[0], tr1 = pTR[1], tr2 = pTR[W], tr3 = pTR[W + 1];
        px4 bl0 = pBL[0], bl1 = pBL[1], bl2 = pBL[W], bl3 = pBL[W + 1];
        px4 br0 = pBR[0], br1 = pBR[1], br2 = pBR[W], br3 = pBR[W + 1];
        h2 wxL = __builtin_bit_cast(h2, xd.y), wxR = __builtin_bit_cast(h2, xd.w);
        h2 wyT = __builtin_bit_cast(h2, yd.y), wyB = __builtin_bit_cast(h2, yd.w);
        finish(lerp2(tl0, tl1, tl2, tl3, wxL, wyT),
               lerp2(tr0, tr1, tr2, tr3, wxR, wyT),
               lerp2(bl0, bl1, bl2, bl3, wxL, wyB),
               lerp2(br0, br1, br2, br3, wxR, wyB), rl, s49);
    };

    // 6272 quads over 512 threads: 6 pair-rounds + tail for t<128
    #pragma unroll
    for (int k = 0; k < 6; ++k) do_pair(t + (2 * k) * THREADS, t + (2 * k + 1) * THREADS);
    if (t < 128) do_single(t + 12 * THREADS);
}

extern "C" void kernel_launch(void* const* d_in, const int* in_sizes, int n_in,
                              void* d_out, int out_size, void* d_ws, size_t ws_size,
                              hipStream_t stream) {
    const float* bottom = (const float*)d_in[0];
    const float* rois   = (const float*)d_in[1];
    float* out = (float*)d_out;

    dim3 grid(NG, RSPLIT); // 128 x 4 = 512 blocks
    roialign_fused<<<grid, THREADS, 0, stream>>>(bottom, rois, out);
}